// Round 9
// baseline (304.029 us; speedup 1.0000x reference)
//
#include <hip/hip_runtime.h>
#include <stdint.h>

#define NB 64
#define SEQL 512
#define L 510
#define T 9
#define H 768
#define LN2 0.6931471805599453f

__device__ __forceinline__ float rl(float v, int l) {
  return __uint_as_float(__builtin_amdgcn_readlane(__float_as_uint(v), l));
}

// ---------------- K1: emissions + in-block chunk scans + numerator terms ----
// Grid: 64 batches x 16 chunk-groups (1024 blocks; was 8x64-row groups/512).
// Block (b,c) computes em rows [32c, 32c+32] (33 rows; the +1 row makes chunk
// c fully block-local) in LDS, then: (a) numerator terms sel[b][l] for
// l in [32c,32c+32), (b) c==0 writes em row 0 to em0, (c) wave0 runs the den
// scan and wave1 the viterbi scan (with backpointers) for chunk c.
// Rationale (r8 postmortem): the 512-block version had 2 waves/SIMD (minimum
// TLP) and was ~70% latency-wait (VALUBusy 30% at 100us). 1024 blocks x
// launch_bounds(256,4) -> 4 waves/SIMD, ~31 KB LDS -> 4 blocks/CU.
// CRITICAL (rule #20): E[81]/t_[81] are indexed ONLY with compile-time
// constants (dynamic init reads go through LDS s_tr) else they spill.
__global__ __launch_bounds__(256, 4) void emis_chunk_kernel(
    const float* __restrict__ hidden, const float* __restrict__ weight,
    const float* __restrict__ bias, const float* __restrict__ trans,
    const float* __restrict__ start_t, const float* __restrict__ end_t,
    const int* __restrict__ labels, float* __restrict__ sel,
    float* __restrict__ em0, float* __restrict__ PdLn, float* __restrict__ Mv,
    unsigned long long* __restrict__ Bp, float* __restrict__ out) {
  __shared__ float4 wl[T * 192];                 // 27648 B: 9 x 768 floats
  __shared__ __align__(16) float s_em[33][12];   // local rows 0..32
  __shared__ __align__(16) float s_ee[33][12];
  __shared__ float s_tr[81];                     // trans staged for dynamic reads
  const float4* w4 = (const float4*)weight;
  for (int k = threadIdx.x; k < T * 192; k += 256) wl[k] = w4[k];
  if (threadIdx.x < 81) s_tr[threadIdx.x] = trans[threadIdx.x];
  if (blockIdx.x == 0 && threadIdx.x == 0) out[0] = 0.f;  // atomic target init
  __syncthreads();
  const int b = blockIdx.x >> 4;
  const int c = blockIdx.x & 15;                 // chunk id in [0,16)
  const int R0 = c * 32;                         // em-row base of this block
  const int lane = threadIdx.x & 63;
  const int wv = threadIdx.x >> 6;
  // ---- emission phase: wave wv owns local rows wv*8 .. wv*8+7 (4 pairs);
  //      wave 0 additionally computes local row 32 (first row of next chunk)
  //      as a 5th (single-row) pair. Software-pipelined as in the 222.7 run.
  const int npair = (wv == 0) ? 5 : 4;
  int i0c, i1c;
  bool v0c, v1c;
  float4 ca[3], cb[3];
  {
    i0c = wv * 8;
    i1c = i0c + 1;
    const int r0 = R0 + i0c, r1 = R0 + i1c;
    v0c = (r0 < L);
    v1c = (r1 < L);
    const int c0 = v0c ? r0 : 0;
    const int c1 = (r1 < L) ? r1 : 0;
    const float4* h0 = (const float4*)(hidden + ((size_t)(b * SEQL + c0 + 1)) * H);
    const float4* h1 = (const float4*)(hidden + ((size_t)(b * SEQL + c1 + 1)) * H);
#pragma unroll
    for (int k = 0; k < 3; ++k) { ca[k] = h0[lane + 64 * k]; cb[k] = h1[lane + 64 * k]; }
  }
#pragma unroll 1
  for (int pr = 0; pr < npair; ++pr) {
    float4 na[3], nb[3];
    int i0n = 0, i1n = 0;
    bool v0n = false, v1n = false;
    if (pr + 1 < npair) {                        // prefetch next pair
      const int prn = pr + 1;
      i0n = (prn < 4) ? (wv * 8 + prn * 2) : 32;
      i1n = (prn < 4) ? (i0n + 1) : 32;
      const int r0 = R0 + i0n, r1 = R0 + i1n;
      v0n = (r0 < L);
      v1n = (r1 < L) && (prn < 4);               // 5th pair: single row
      const int c0 = v0n ? r0 : 0;
      const int c1 = (r1 < L) ? r1 : 0;
      const float4* h0 = (const float4*)(hidden + ((size_t)(b * SEQL + c0 + 1)) * H);
      const float4* h1 = (const float4*)(hidden + ((size_t)(b * SEQL + c1 + 1)) * H);
#pragma unroll
      for (int k = 0; k < 3; ++k) { na[k] = h0[lane + 64 * k]; nb[k] = h1[lane + 64 * k]; }
    }
    float a0[T], a1[T];
#pragma unroll
    for (int t = 0; t < T; ++t) { a0[t] = 0.f; a1[t] = 0.f; }
#pragma unroll
    for (int t = 0; t < T; ++t) {
#pragma unroll
      for (int k = 0; k < 3; ++k) {
        float4 w = wl[t * 192 + lane + 64 * k];  // shared by both rows
        a0[t] = fmaf(ca[k].x, w.x, fmaf(ca[k].y, w.y, fmaf(ca[k].z, w.z, fmaf(ca[k].w, w.w, a0[t]))));
        a1[t] = fmaf(cb[k].x, w.x, fmaf(cb[k].y, w.y, fmaf(cb[k].z, w.z, fmaf(cb[k].w, w.w, a1[t]))));
      }
    }
#pragma unroll
    for (int off = 32; off; off >>= 1) {
#pragma unroll
      for (int t = 0; t < T; ++t) {
        a0[t] += __shfl_xor(a0[t], off);
        a1[t] += __shfl_xor(a1[t], off);
      }
    }
    if (lane < 2) {
      const bool vv = lane ? v1c : v0c;
      const int ii = lane ? i1c : i0c;
      if (vv) {
#pragma unroll
        for (int t = 0; t < T; ++t) {
          float v = (lane ? a1[t] : a0[t]) + bias[t];
          s_em[ii][t] = v;
          s_ee[ii][t] = __expf(v);
        }
      }
    }
    if (pr + 1 < npair) {                        // rotate pipeline
#pragma unroll
      for (int k = 0; k < 3; ++k) { ca[k] = na[k]; cb[k] = nb[k]; }
      i0c = i0n; i1c = i1n; v0c = v0n; v1c = v1n;
    }
  }
  __syncthreads();
  // ---- numerator terms for this block's rows (exact per-term rounding kept:
  //      term(l=0) = start+e; else trans+e; end term stored separately) ------
  if (threadIdx.x < 32) {
    const int r = threadIdx.x;
    const int l = R0 + r;
    if (l < L) {
      const int tg = labels[b * SEQL + 1 + l];
      const float e = s_em[r][tg];
      float term;
      if (l == 0) term = start_t[tg] + e;
      else term = s_tr[labels[b * SEQL + l] * 9 + tg] + e;
      sel[b * 512 + l] = term;
      if (l == L - 1) sel[b * 512 + 510] = end_t[tg];
    }
  }
  if (c == 0 && threadIdx.x < 12) em0[b * 12 + threadIdx.x] = s_em[0][threadIdx.x];
  // ---- chunk-scan phase: wv0 = den, wv1 = viterbi for chunk c --------------
  const int task = b * 16 + c;
  const int nt = (c == 15) ? 29 : 32;
  const int i9 = (lane < 9) ? lane : 8;
  if (wv == 0) {
    // ---- den: running 9x9 transfer-matrix row in prob space + rescale ----
    // E[] is static-indexed only (stays in VGPRs); dynamic init reads s_tr.
    float E[81];
#pragma unroll
    for (int k = 0; k < 81; ++k) E[k] = __expf(s_tr[k]);
    float R[9];
#pragma unroll
    for (int j = 0; j < 9; ++j) R[j] = __expf(s_tr[i9 * 9 + j]) * s_ee[1][j];
    int iexp = 0;
    for (int t = 1; t < nt; ++t) {
      float Rn[9];
#pragma unroll
      for (int j = 0; j < 9; ++j) {
        float a = R[0] * E[j];
#pragma unroll
        for (int k = 1; k < 9; ++k) a = fmaf(R[k], E[k * 9 + j], a);
        Rn[j] = a;
      }
#pragma unroll
      for (int j = 0; j < 9; ++j) R[j] = Rn[j] * s_ee[1 + t][j];
      if ((t & 3) == 0) {  // power-of-2 rescale
        float mx = R[0];
#pragma unroll
        for (int j = 1; j < 9; ++j) mx = fmaxf(mx, R[j]);
        int ex = (int)((__float_as_uint(mx) >> 23) & 0xff) - 127;
        iexp += ex;
        float sc = __uint_as_float((uint32_t)(127 - ex) << 23);
#pragma unroll
        for (int j = 0; j < 9; ++j) R[j] *= sc;
      }
    }
    if (lane < 9) {
      float ls = (float)iexp * LN2;
#pragma unroll
      for (int j = 0; j < 9; ++j)
        PdLn[(size_t)task * 81 + j * 9 + i9] = __logf(R[j]) + ls;
    }
  } else if (wv == 1) {
    // ---- viterbi max-plus transfer matrix, WITH backpointer recording ----
    // t_[] static-indexed only; dynamic init reads s_tr.
    float t_[81];
#pragma unroll
    for (int k = 0; k < 81; ++k) t_[k] = s_tr[k];
    float V[9];
#pragma unroll
    for (int j = 0; j < 9; ++j) V[j] = s_tr[i9 * 9 + j] + s_em[1][j];
    for (int t = 1; t < nt; ++t) {
      uint32_t lo = 0, hi = 0;
      float Vn[9];
#pragma unroll
      for (int j = 0; j < 9; ++j) {
        float best = V[0] + t_[0 * 9 + j];
        int bi = 0;
#pragma unroll
        for (int k = 1; k < 9; ++k) {
          float v = V[k] + t_[k * 9 + j];
          if (v > best) { best = v; bi = k; }
        }
        Vn[j] = best + s_em[1 + t][j];
        if (j < 8) lo |= ((uint32_t)bi) << (4 * j);
        else hi = (uint32_t)bi;
      }
      if (lane < 9)
        Bp[(size_t)task * 288 + t * 9 + i9] =
            (unsigned long long)lo | ((unsigned long long)hi << 32);
#pragma unroll
      for (int j = 0; j < 9; ++j) V[j] = Vn[j];
    }
    if (lane < 9) {
#pragma unroll
      for (int j = 0; j < 9; ++j)
        Mv[(size_t)task * 81 + j * 9 + i9] = V[j];  // column-major [j][i]
    }
  }
}

// ---------------- K2: per-batch compose (256 thr, parallel waves) -----------
// Verbatim from the 222.7-us run (r4). wave0: numerator + den LSE + loss
// atomic. wave1: viterbi compose + chase. wave2: backtrack from staged bp.
__global__ __launch_bounds__(256) void compose_kernel(
    const float* __restrict__ sel, const float* __restrict__ em0,
    const float* __restrict__ PdLn, const float* __restrict__ Mv,
    const unsigned long long* __restrict__ Bp,
    const float* __restrict__ start_t, const float* __restrict__ end_t,
    float* __restrict__ out) {
  __shared__ __align__(16) float s_pd[16 * 81];
  __shared__ __align__(16) float s_mv[16 * 81];
  __shared__ __align__(16) unsigned long long s_bp[16 * 290];  // +2 u64 pad/chunk
  __shared__ float s_A[17 * 9];
  __shared__ int s_ch[16][2];
  const int b = blockIdx.x;
  const int tid = threadIdx.x;
  // ---- stage (all 256 threads, coalesced float4) ----
  {
    const float4* pdg = (const float4*)(PdLn + (size_t)b * 1296);
    const float4* mvg = (const float4*)(Mv + (size_t)b * 1296);
    for (int k = tid; k < 324; k += 256) {
      ((float4*)s_pd)[k] = pdg[k];
      ((float4*)s_mv)[k] = mvg[k];
    }
    const float4* bpg = (const float4*)(Bp + (size_t)b * 4608);
    for (int k = tid; k < 2304; k += 256) {
      const int s = k / 144, r = k - s * 144;
      ((float4*)&s_bp[s * 290])[r] = bpg[k];
    }
  }
  __syncthreads();
  const int wv = tid >> 6;
  const int lane = tid & 63;
  const int jj = lane < 9 ? lane : 8;

  if (wv == 0) {
    // ---- numerator: identical accumulation order ----
    float part_ = 0.f;
    for (int l = lane; l < L; l += 64) part_ += sel[b * 512 + l];
    if (lane == 61) part_ += sel[b * 512 + 510];  // end-term (l=509 -> lane 61)
#pragma unroll
    for (int off = 32; off; off >>= 1) part_ += __shfl_xor(part_, off);
    // ---- denominator: 16 LSE compose steps, lane j ----
    float D = start_t[jj] + em0[b * 12 + jj];
    for (int u = 0; u < 16; ++u) {
      const float* col = &s_pd[u * 81 + jj * 9];
      float v0 = rl(D, 0) + col[0], v1 = rl(D, 1) + col[1], v2 = rl(D, 2) + col[2];
      float v3 = rl(D, 3) + col[3], v4 = rl(D, 4) + col[4], v5 = rl(D, 5) + col[5];
      float v6 = rl(D, 6) + col[6], v7 = rl(D, 7) + col[7], v8 = rl(D, 8) + col[8];
      float mx = fmaxf(fmaxf(fmaxf(fmaxf(v0, v1), fmaxf(v2, v3)),
                             fmaxf(fmaxf(v4, v5), fmaxf(v6, v7))), v8);
      float sum = __expf(v0 - mx) + __expf(v1 - mx) + __expf(v2 - mx) +
                  __expf(v3 - mx) + __expf(v4 - mx) + __expf(v5 - mx) +
                  __expf(v6 - mx) + __expf(v7 - mx) + __expf(v8 - mx);
      D = mx + __logf(sum);
    }
    float fe = D + end_t[jj];
    float w0 = rl(fe, 0), w1 = rl(fe, 1), w2 = rl(fe, 2), w3 = rl(fe, 3);
    float w4 = rl(fe, 4), w5 = rl(fe, 5), w6 = rl(fe, 6), w7 = rl(fe, 7), w8 = rl(fe, 8);
    float mx = fmaxf(fmaxf(fmaxf(fmaxf(w0, w1), fmaxf(w2, w3)),
                           fmaxf(fmaxf(w4, w5), fmaxf(w6, w7))), w8);
    float den = mx + __logf(__expf(w0 - mx) + __expf(w1 - mx) + __expf(w2 - mx) +
                            __expf(w3 - mx) + __expf(w4 - mx) + __expf(w5 - mx) +
                            __expf(w6 - mx) + __expf(w7 - mx) + __expf(w8 - mx));
    if (lane == 0) atomicAdd(out, den - part_);  // out[0] = -sum(llh)
  } else if (wv == 1) {
    // ---- viterbi boundary alphas (max-plus compose), lane j ----
    float A = start_t[jj] + em0[b * 12 + jj];
    if (lane < 9) s_A[lane] = A;
    for (int u = 0; u < 16; ++u) {
      const float* col = &s_mv[u * 81 + jj * 9];
      float u0 = rl(A, 0) + col[0], u1 = rl(A, 1) + col[1], u2 = rl(A, 2) + col[2];
      float u3 = rl(A, 3) + col[3], u4 = rl(A, 4) + col[4], u5 = rl(A, 5) + col[5];
      float u6 = rl(A, 6) + col[6], u7 = rl(A, 7) + col[7], u8 = rl(A, 8) + col[8];
      A = fmaxf(fmaxf(fmaxf(fmaxf(u0, u1), fmaxf(u2, u3)),
                      fmaxf(fmaxf(u4, u5), fmaxf(u6, u7))), u8);
      if (lane < 9) s_A[(u + 1) * 9 + lane] = A;
    }
    // last tag: first-index argmax of A + end
    float fv = A + end_t[jj];
    int j = 0;
    {
      float bv = rl(fv, 0);
#pragma unroll
      for (int i = 1; i < 9; ++i) { float v = rl(fv, i); if (v > bv) { bv = v; j = i; } }
    }
    // ---- chunk-level backward chase ----
    for (int u = 15; u >= 0; --u) {
      float val = s_A[u * 9 + jj] + s_mv[u * 81 + j * 9 + jj];  // lane = entry state i
      int ii = 0;
      float bb = rl(val, 0);
#pragma unroll
      for (int i = 1; i < 9; ++i) { float v = rl(val, i); if (v > bb) { bb = v; ii = i; } }
      if (lane == 0) { s_ch[u][0] = ii; s_ch[u][1] = j; }
      j = ii;
    }
    if (lane == 0) out[1 + (size_t)b * L] = (float)j;  // tag at position 0
  }
  __syncthreads();
  // ---- per-chunk backtrack from backpointers (lane = chunk) ----
  if (wv == 2 && lane < 16) {
    const int s = lane;
    const int nt = (s == 15) ? 29 : 32;
    const int lb = 32 * s + 1;
    const int i0 = s_ch[s][0];
    int cur = s_ch[s][1];
    float* orow = out + 1 + (size_t)b * L + lb;
    for (int q = nt - 1; q >= 1; --q) {
      orow[q] = (float)cur;
      unsigned long long w = s_bp[s * 290 + q * 9 + i0];
      cur = (int)((w >> (4 * cur)) & 15ULL);
    }
    orow[0] = (float)cur;
  }
}

extern "C" void kernel_launch(void* const* d_in, const int* in_sizes, int n_in,
                              void* d_out, int out_size, void* d_ws, size_t ws_size,
                              hipStream_t stream) {
  const float* hidden  = (const float*)d_in[0];
  const int*   labels  = (const int*)d_in[1];
  const float* weight  = (const float*)d_in[2];
  const float* bias    = (const float*)d_in[3];
  const float* start_t = (const float*)d_in[4];
  const float* end_t   = (const float*)d_in[5];
  const float* trans   = (const float*)d_in[6];
  float* out = (float*)d_out;

  // workspace layout (16B-aligned blocks): ~3.16 MB total
  unsigned long long* Bp = (unsigned long long*)d_ws;   // 1024*288 u64 = 2359296 B
  float* sel  = (float*)(Bp + (size_t)1024 * 288);      // 64*512 f   =  131072 B
  float* em0  = sel + (size_t)64 * 512;                 // 64*12 f    =    3072 B
  float* PdLn = em0 + 768;                              // 1024*81 f  =  331776 B
  float* Mv   = PdLn + (size_t)1024 * 81;               // 1024*81 f  =  331776 B

  emis_chunk_kernel<<<1024, 256, 0, stream>>>(hidden, weight, bias, trans,
                                              start_t, end_t, labels,
                                              sel, em0, PdLn, Mv, Bp, out);
  compose_kernel<<<NB, 256, 0, stream>>>(sel, em0, PdLn, Mv, Bp,
                                         start_t, end_t, out);
}

// Round 10
// 234.292 us; speedup vs baseline: 1.2977x; 1.2977x over previous
//
#include <hip/hip_runtime.h>
#include <stdint.h>

#define NB 64
#define SEQL 512
#define L 510
#define T 9
#define H 768
#define LN2 0.6931471805599453f

__device__ __forceinline__ float rl(float v, int l) {
  return __uint_as_float(__builtin_amdgcn_readlane(__float_as_uint(v), l));
}

// ---------------- K1: emissions + in-block chunk scans + numerator terms ----
// Grid: 64 batches x 16 chunk-groups (1024 blocks). Block (b,c) computes em
// rows [32c, 32c+32] (33 rows; +1 row makes chunk c block-local) in LDS, then:
// (a) numerator terms sel[b][l], (b) c==0 writes em row 0 to em0, (c) wave0
// runs the den scan and wave1 the viterbi scan (with backpointers) for chunk c.
// OCCUPANCY (r9 postmortem): __launch_bounds__(256,4) capped VGPR at 128 and
// re-spilled the scan arrays (WRITE_SIZE 3MB->192MB, dur 100->177us). The cap
// is unnecessary: ~108 VGPRs already permits 4 waves/SIMD (halving points are
// 64/128/256), and 31KB LDS permits 4 blocks/CU. So: (256,2) bounds + 1024
// blocks gives the TLP without the spill.
// CRITICAL (rule #20): E[81]/t_[81] are indexed ONLY with compile-time
// constants (dynamic init reads go through LDS s_tr) else they spill.
__global__ __launch_bounds__(256, 2) void emis_chunk_kernel(
    const float* __restrict__ hidden, const float* __restrict__ weight,
    const float* __restrict__ bias, const float* __restrict__ trans,
    const float* __restrict__ start_t, const float* __restrict__ end_t,
    const int* __restrict__ labels, float* __restrict__ sel,
    float* __restrict__ em0, float* __restrict__ PdLn, float* __restrict__ Mv,
    unsigned long long* __restrict__ Bp, float* __restrict__ out) {
  __shared__ float4 wl[T * 192];                 // 27648 B: 9 x 768 floats
  __shared__ __align__(16) float s_em[33][12];   // local rows 0..32
  __shared__ __align__(16) float s_ee[33][12];
  __shared__ float s_tr[81];                     // trans staged for dynamic reads
  const float4* w4 = (const float4*)weight;
  for (int k = threadIdx.x; k < T * 192; k += 256) wl[k] = w4[k];
  if (threadIdx.x < 81) s_tr[threadIdx.x] = trans[threadIdx.x];
  if (blockIdx.x == 0 && threadIdx.x == 0) out[0] = 0.f;  // atomic target init
  __syncthreads();
  const int b = blockIdx.x >> 4;
  const int c = blockIdx.x & 15;                 // chunk id in [0,16)
  const int R0 = c * 32;                         // em-row base of this block
  const int lane = threadIdx.x & 63;
  const int wv = threadIdx.x >> 6;
  // ---- emission phase: wave wv owns local rows wv*8 .. wv*8+7 (4 pairs);
  //      wave 0 additionally computes local row 32 (first row of next chunk)
  //      as a 5th (single-row) pair. Software-pipelined as in the 222.7 run.
  const int npair = (wv == 0) ? 5 : 4;
  int i0c, i1c;
  bool v0c, v1c;
  float4 ca[3], cb[3];
  {
    i0c = wv * 8;
    i1c = i0c + 1;
    const int r0 = R0 + i0c, r1 = R0 + i1c;
    v0c = (r0 < L);
    v1c = (r1 < L);
    const int c0 = v0c ? r0 : 0;
    const int c1 = (r1 < L) ? r1 : 0;
    const float4* h0 = (const float4*)(hidden + ((size_t)(b * SEQL + c0 + 1)) * H);
    const float4* h1 = (const float4*)(hidden + ((size_t)(b * SEQL + c1 + 1)) * H);
#pragma unroll
    for (int k = 0; k < 3; ++k) { ca[k] = h0[lane + 64 * k]; cb[k] = h1[lane + 64 * k]; }
  }
#pragma unroll 1
  for (int pr = 0; pr < npair; ++pr) {
    float4 na[3], nb[3];
    int i0n = 0, i1n = 0;
    bool v0n = false, v1n = false;
    if (pr + 1 < npair) {                        // prefetch next pair
      const int prn = pr + 1;
      i0n = (prn < 4) ? (wv * 8 + prn * 2) : 32;
      i1n = (prn < 4) ? (i0n + 1) : 32;
      const int r0 = R0 + i0n, r1 = R0 + i1n;
      v0n = (r0 < L);
      v1n = (r1 < L) && (prn < 4);               // 5th pair: single row
      const int c0 = v0n ? r0 : 0;
      const int c1 = (r1 < L) ? r1 : 0;
      const float4* h0 = (const float4*)(hidden + ((size_t)(b * SEQL + c0 + 1)) * H);
      const float4* h1 = (const float4*)(hidden + ((size_t)(b * SEQL + c1 + 1)) * H);
#pragma unroll
      for (int k = 0; k < 3; ++k) { na[k] = h0[lane + 64 * k]; nb[k] = h1[lane + 64 * k]; }
    }
    float a0[T], a1[T];
#pragma unroll
    for (int t = 0; t < T; ++t) { a0[t] = 0.f; a1[t] = 0.f; }
#pragma unroll
    for (int t = 0; t < T; ++t) {
#pragma unroll
      for (int k = 0; k < 3; ++k) {
        float4 w = wl[t * 192 + lane + 64 * k];  // shared by both rows
        a0[t] = fmaf(ca[k].x, w.x, fmaf(ca[k].y, w.y, fmaf(ca[k].z, w.z, fmaf(ca[k].w, w.w, a0[t]))));
        a1[t] = fmaf(cb[k].x, w.x, fmaf(cb[k].y, w.y, fmaf(cb[k].z, w.z, fmaf(cb[k].w, w.w, a1[t]))));
      }
    }
#pragma unroll
    for (int off = 32; off; off >>= 1) {
#pragma unroll
      for (int t = 0; t < T; ++t) {
        a0[t] += __shfl_xor(a0[t], off);
        a1[t] += __shfl_xor(a1[t], off);
      }
    }
    if (lane < 2) {
      const bool vv = lane ? v1c : v0c;
      const int ii = lane ? i1c : i0c;
      if (vv) {
#pragma unroll
        for (int t = 0; t < T; ++t) {
          float v = (lane ? a1[t] : a0[t]) + bias[t];
          s_em[ii][t] = v;
          s_ee[ii][t] = __expf(v);
        }
      }
    }
    if (pr + 1 < npair) {                        // rotate pipeline
#pragma unroll
      for (int k = 0; k < 3; ++k) { ca[k] = na[k]; cb[k] = nb[k]; }
      i0c = i0n; i1c = i1n; v0c = v0n; v1c = v1n;
    }
  }
  __syncthreads();
  // ---- numerator terms for this block's rows (exact per-term rounding kept:
  //      term(l=0) = start+e; else trans+e; end term stored separately) ------
  if (threadIdx.x < 32) {
    const int r = threadIdx.x;
    const int l = R0 + r;
    if (l < L) {
      const int tg = labels[b * SEQL + 1 + l];
      const float e = s_em[r][tg];
      float term;
      if (l == 0) term = start_t[tg] + e;
      else term = s_tr[labels[b * SEQL + l] * 9 + tg] + e;
      sel[b * 512 + l] = term;
      if (l == L - 1) sel[b * 512 + 510] = end_t[tg];
    }
  }
  if (c == 0 && threadIdx.x < 12) em0[b * 12 + threadIdx.x] = s_em[0][threadIdx.x];
  // ---- chunk-scan phase: wv0 = den, wv1 = viterbi for chunk c --------------
  const int task = b * 16 + c;
  const int nt = (c == 15) ? 29 : 32;
  const int i9 = (lane < 9) ? lane : 8;
  if (wv == 0) {
    // ---- den: running 9x9 transfer-matrix row in prob space + rescale ----
    // E[] is static-indexed only (stays in VGPRs); dynamic init reads s_tr.
    float E[81];
#pragma unroll
    for (int k = 0; k < 81; ++k) E[k] = __expf(s_tr[k]);
    float R[9];
#pragma unroll
    for (int j = 0; j < 9; ++j) R[j] = __expf(s_tr[i9 * 9 + j]) * s_ee[1][j];
    int iexp = 0;
    for (int t = 1; t < nt; ++t) {
      float Rn[9];
#pragma unroll
      for (int j = 0; j < 9; ++j) {
        float a = R[0] * E[j];
#pragma unroll
        for (int k = 1; k < 9; ++k) a = fmaf(R[k], E[k * 9 + j], a);
        Rn[j] = a;
      }
#pragma unroll
      for (int j = 0; j < 9; ++j) R[j] = Rn[j] * s_ee[1 + t][j];
      if ((t & 3) == 0) {  // power-of-2 rescale
        float mx = R[0];
#pragma unroll
        for (int j = 1; j < 9; ++j) mx = fmaxf(mx, R[j]);
        int ex = (int)((__float_as_uint(mx) >> 23) & 0xff) - 127;
        iexp += ex;
        float sc = __uint_as_float((uint32_t)(127 - ex) << 23);
#pragma unroll
        for (int j = 0; j < 9; ++j) R[j] *= sc;
      }
    }
    if (lane < 9) {
      float ls = (float)iexp * LN2;
#pragma unroll
      for (int j = 0; j < 9; ++j)
        PdLn[(size_t)task * 81 + j * 9 + i9] = __logf(R[j]) + ls;
    }
  } else if (wv == 1) {
    // ---- viterbi max-plus transfer matrix, WITH backpointer recording ----
    // t_[] static-indexed only; dynamic init reads s_tr.
    float t_[81];
#pragma unroll
    for (int k = 0; k < 81; ++k) t_[k] = s_tr[k];
    float V[9];
#pragma unroll
    for (int j = 0; j < 9; ++j) V[j] = s_tr[i9 * 9 + j] + s_em[1][j];
    for (int t = 1; t < nt; ++t) {
      uint32_t lo = 0, hi = 0;
      float Vn[9];
#pragma unroll
      for (int j = 0; j < 9; ++j) {
        float best = V[0] + t_[0 * 9 + j];
        int bi = 0;
#pragma unroll
        for (int k = 1; k < 9; ++k) {
          float v = V[k] + t_[k * 9 + j];
          if (v > best) { best = v; bi = k; }
        }
        Vn[j] = best + s_em[1 + t][j];
        if (j < 8) lo |= ((uint32_t)bi) << (4 * j);
        else hi = (uint32_t)bi;
      }
      if (lane < 9)
        Bp[(size_t)task * 288 + t * 9 + i9] =
            (unsigned long long)lo | ((unsigned long long)hi << 32);
#pragma unroll
      for (int j = 0; j < 9; ++j) V[j] = Vn[j];
    }
    if (lane < 9) {
#pragma unroll
      for (int j = 0; j < 9; ++j)
        Mv[(size_t)task * 81 + j * 9 + i9] = V[j];  // column-major [j][i]
    }
  }
}

// ---------------- K2: per-batch compose (256 thr, parallel waves) -----------
// Verbatim from the 222.7-us run (r4). wave0: numerator + den LSE + loss
// atomic. wave1: viterbi compose + chase. wave2: backtrack from staged bp.
__global__ __launch_bounds__(256) void compose_kernel(
    const float* __restrict__ sel, const float* __restrict__ em0,
    const float* __restrict__ PdLn, const float* __restrict__ Mv,
    const unsigned long long* __restrict__ Bp,
    const float* __restrict__ start_t, const float* __restrict__ end_t,
    float* __restrict__ out) {
  __shared__ __align__(16) float s_pd[16 * 81];
  __shared__ __align__(16) float s_mv[16 * 81];
  __shared__ __align__(16) unsigned long long s_bp[16 * 290];  // +2 u64 pad/chunk
  __shared__ float s_A[17 * 9];
  __shared__ int s_ch[16][2];
  const int b = blockIdx.x;
  const int tid = threadIdx.x;
  // ---- stage (all 256 threads, coalesced float4) ----
  {
    const float4* pdg = (const float4*)(PdLn + (size_t)b * 1296);
    const float4* mvg = (const float4*)(Mv + (size_t)b * 1296);
    for (int k = tid; k < 324; k += 256) {
      ((float4*)s_pd)[k] = pdg[k];
      ((float4*)s_mv)[k] = mvg[k];
    }
    const float4* bpg = (const float4*)(Bp + (size_t)b * 4608);
    for (int k = tid; k < 2304; k += 256) {
      const int s = k / 144, r = k - s * 144;
      ((float4*)&s_bp[s * 290])[r] = bpg[k];
    }
  }
  __syncthreads();
  const int wv = tid >> 6;
  const int lane = tid & 63;
  const int jj = lane < 9 ? lane : 8;

  if (wv == 0) {
    // ---- numerator: identical accumulation order ----
    float part_ = 0.f;
    for (int l = lane; l < L; l += 64) part_ += sel[b * 512 + l];
    if (lane == 61) part_ += sel[b * 512 + 510];  // end-term (l=509 -> lane 61)
#pragma unroll
    for (int off = 32; off; off >>= 1) part_ += __shfl_xor(part_, off);
    // ---- denominator: 16 LSE compose steps, lane j ----
    float D = start_t[jj] + em0[b * 12 + jj];
    for (int u = 0; u < 16; ++u) {
      const float* col = &s_pd[u * 81 + jj * 9];
      float v0 = rl(D, 0) + col[0], v1 = rl(D, 1) + col[1], v2 = rl(D, 2) + col[2];
      float v3 = rl(D, 3) + col[3], v4 = rl(D, 4) + col[4], v5 = rl(D, 5) + col[5];
      float v6 = rl(D, 6) + col[6], v7 = rl(D, 7) + col[7], v8 = rl(D, 8) + col[8];
      float mx = fmaxf(fmaxf(fmaxf(fmaxf(v0, v1), fmaxf(v2, v3)),
                             fmaxf(fmaxf(v4, v5), fmaxf(v6, v7))), v8);
      float sum = __expf(v0 - mx) + __expf(v1 - mx) + __expf(v2 - mx) +
                  __expf(v3 - mx) + __expf(v4 - mx) + __expf(v5 - mx) +
                  __expf(v6 - mx) + __expf(v7 - mx) + __expf(v8 - mx);
      D = mx + __logf(sum);
    }
    float fe = D + end_t[jj];
    float w0 = rl(fe, 0), w1 = rl(fe, 1), w2 = rl(fe, 2), w3 = rl(fe, 3);
    float w4 = rl(fe, 4), w5 = rl(fe, 5), w6 = rl(fe, 6), w7 = rl(fe, 7), w8 = rl(fe, 8);
    float mx = fmaxf(fmaxf(fmaxf(fmaxf(w0, w1), fmaxf(w2, w3)),
                           fmaxf(fmaxf(w4, w5), fmaxf(w6, w7))), w8);
    float den = mx + __logf(__expf(w0 - mx) + __expf(w1 - mx) + __expf(w2 - mx) +
                            __expf(w3 - mx) + __expf(w4 - mx) + __expf(w5 - mx) +
                            __expf(w6 - mx) + __expf(w7 - mx) + __expf(w8 - mx));
    if (lane == 0) atomicAdd(out, den - part_);  // out[0] = -sum(llh)
  } else if (wv == 1) {
    // ---- viterbi boundary alphas (max-plus compose), lane j ----
    float A = start_t[jj] + em0[b * 12 + jj];
    if (lane < 9) s_A[lane] = A;
    for (int u = 0; u < 16; ++u) {
      const float* col = &s_mv[u * 81 + jj * 9];
      float u0 = rl(A, 0) + col[0], u1 = rl(A, 1) + col[1], u2 = rl(A, 2) + col[2];
      float u3 = rl(A, 3) + col[3], u4 = rl(A, 4) + col[4], u5 = rl(A, 5) + col[5];
      float u6 = rl(A, 6) + col[6], u7 = rl(A, 7) + col[7], u8 = rl(A, 8) + col[8];
      A = fmaxf(fmaxf(fmaxf(fmaxf(u0, u1), fmaxf(u2, u3)),
                      fmaxf(fmaxf(u4, u5), fmaxf(u6, u7))), u8);
      if (lane < 9) s_A[(u + 1) * 9 + lane] = A;
    }
    // last tag: first-index argmax of A + end
    float fv = A + end_t[jj];
    int j = 0;
    {
      float bv = rl(fv, 0);
#pragma unroll
      for (int i = 1; i < 9; ++i) { float v = rl(fv, i); if (v > bv) { bv = v; j = i; } }
    }
    // ---- chunk-level backward chase ----
    for (int u = 15; u >= 0; --u) {
      float val = s_A[u * 9 + jj] + s_mv[u * 81 + j * 9 + jj];  // lane = entry state i
      int ii = 0;
      float bb = rl(val, 0);
#pragma unroll
      for (int i = 1; i < 9; ++i) { float v = rl(val, i); if (v > bb) { bb = v; ii = i; } }
      if (lane == 0) { s_ch[u][0] = ii; s_ch[u][1] = j; }
      j = ii;
    }
    if (lane == 0) out[1 + (size_t)b * L] = (float)j;  // tag at position 0
  }
  __syncthreads();
  // ---- per-chunk backtrack from backpointers (lane = chunk) ----
  if (wv == 2 && lane < 16) {
    const int s = lane;
    const int nt = (s == 15) ? 29 : 32;
    const int lb = 32 * s + 1;
    const int i0 = s_ch[s][0];
    int cur = s_ch[s][1];
    float* orow = out + 1 + (size_t)b * L + lb;
    for (int q = nt - 1; q >= 1; --q) {
      orow[q] = (float)cur;
      unsigned long long w = s_bp[s * 290 + q * 9 + i0];
      cur = (int)((w >> (4 * cur)) & 15ULL);
    }
    orow[0] = (float)cur;
  }
}

extern "C" void kernel_launch(void* const* d_in, const int* in_sizes, int n_in,
                              void* d_out, int out_size, void* d_ws, size_t ws_size,
                              hipStream_t stream) {
  const float* hidden  = (const float*)d_in[0];
  const int*   labels  = (const int*)d_in[1];
  const float* weight  = (const float*)d_in[2];
  const float* bias    = (const float*)d_in[3];
  const float* start_t = (const float*)d_in[4];
  const float* end_t   = (const float*)d_in[5];
  const float* trans   = (const float*)d_in[6];
  float* out = (float*)d_out;

  // workspace layout (16B-aligned blocks): ~3.16 MB total
  unsigned long long* Bp = (unsigned long long*)d_ws;   // 1024*288 u64 = 2359296 B
  float* sel  = (float*)(Bp + (size_t)1024 * 288);      // 64*512 f   =  131072 B
  float* em0  = sel + (size_t)64 * 512;                 // 64*12 f    =    3072 B
  float* PdLn = em0 + 768;                              // 1024*81 f  =  331776 B
  float* Mv   = PdLn + (size_t)1024 * 81;               // 1024*81 f  =  331776 B

  emis_chunk_kernel<<<1024, 256, 0, stream>>>(hidden, weight, bias, trans,
                                              start_t, end_t, labels,
                                              sel, em0, PdLn, Mv, Bp, out);
  compose_kernel<<<NB, 256, 0, stream>>>(sel, em0, PdLn, Mv, Bp,
                                         start_t, end_t, out);
}

// Round 12
// 222.457 us; speedup vs baseline: 1.3667x; 1.0532x over previous
//
#include <hip/hip_runtime.h>
#include <stdint.h>

#define NB 64
#define SEQL 512
#define L 510
#define T 9
#define H 768
#define LN2 0.6931471805599453f

__device__ __forceinline__ float rl(float v, int l) {
  return __uint_as_float(__builtin_amdgcn_readlane(__float_as_uint(v), l));
}

// ---------------- K1: emissions + in-block chunk scans + numerator terms ----
// Grid: 64 batches x 8 row-groups. Block (b,p) computes em rows [64p, 64p+64]
// in LDS, then: (a) writes per-position numerator terms sel[b][l], (b) p==0
// writes em row 0 to em0, (c) 4 waves run the 4 chunk scans (den s=2p/2p+1,
// viterbi s=2p/2p+1 with backpointer recording) from LDS.
// BEST-VERIFIED STRUCTURE (222.7us): session evidence r5-r11 shows every
// fusion/persistent/occupancy variant regresses or fails:
//  - last-block election fusion: kernel 150-155us + ~45us timing phantom
//  - spinner-composer single dispatch: container failure
//  - 1024-block K1: 109us (2-wave/SIMD -> 4 did NOT reduce wall)
//  - launch_bounds(256,4): VGPR cap 128 -> 192MB spill
// CRITICAL (rule #20): E[81]/t_[81] are indexed ONLY with compile-time
// constants (dynamic init reads go through LDS s_tr) else they spill (r2/r3:
// 44.5 MB scratch traffic, +80us).
__global__ __launch_bounds__(256, 2) void emis_chunk_kernel(
    const float* __restrict__ hidden, const float* __restrict__ weight,
    const float* __restrict__ bias, const float* __restrict__ trans,
    const float* __restrict__ start_t, const float* __restrict__ end_t,
    const int* __restrict__ labels, float* __restrict__ sel,
    float* __restrict__ em0, float* __restrict__ PdLn, float* __restrict__ Mv,
    unsigned long long* __restrict__ Bp, float* __restrict__ out) {
  __shared__ float4 wl[T * 192];                 // 27648 B: 9 x 768 floats
  __shared__ __align__(16) float s_em[65][12];   // local rows 0..64
  __shared__ __align__(16) float s_ee[65][12];
  __shared__ float s_tr[81];                     // trans staged for dynamic reads
  const float4* w4 = (const float4*)weight;
  for (int k = threadIdx.x; k < T * 192; k += 256) wl[k] = w4[k];
  if (threadIdx.x < 81) s_tr[threadIdx.x] = trans[threadIdx.x];
  if (blockIdx.x == 0 && threadIdx.x == 0) out[0] = 0.f;  // atomic target init
  __syncthreads();
  const int b = blockIdx.x >> 3;
  const int p = blockIdx.x & 7;
  const int row0 = p * 64;                       // em-row base of this block
  const int lane = threadIdx.x & 63;
  const int wv = threadIdx.x >> 6;
  // ---- emission phase: wave wv owns local rows wv*16 .. wv*16+15 (pairs);
  //      wave 0 additionally computes local row 64 (first row of next group).
  //      Software-pipelined: pair pr+1's global loads issue before pair pr's
  //      compute, hiding HBM latency under the FMA/shuffle work.
  const int npair = (wv == 0) ? 9 : 8;
  int i0c, i1c;
  bool v0c, v1c;
  float4 ca[3], cb[3];
  {
    i0c = wv * 16;
    i1c = i0c + 1;
    const int r0 = row0 + i0c, r1 = row0 + i1c;
    v0c = (r0 < L);
    v1c = (r1 < L);
    const int c0 = v0c ? r0 : 0;
    const int c1 = (r1 < L) ? r1 : 0;
    const float4* h0 = (const float4*)(hidden + ((size_t)(b * SEQL + c0 + 1)) * H);
    const float4* h1 = (const float4*)(hidden + ((size_t)(b * SEQL + c1 + 1)) * H);
#pragma unroll
    for (int k = 0; k < 3; ++k) { ca[k] = h0[lane + 64 * k]; cb[k] = h1[lane + 64 * k]; }
  }
#pragma unroll 1
  for (int pr = 0; pr < npair; ++pr) {
    float4 na[3], nb[3];
    int i0n = 0, i1n = 0;
    bool v0n = false, v1n = false;
    if (pr + 1 < npair) {                        // prefetch next pair
      const int prn = pr + 1;
      i0n = (prn < 8) ? (wv * 16 + prn * 2) : 64;
      i1n = (prn < 8) ? (i0n + 1) : 64;
      const int r0 = row0 + i0n, r1 = row0 + i1n;
      v0n = (r0 < L);
      v1n = (r1 < L) && (prn < 8);
      const int c0 = v0n ? r0 : 0;
      const int c1 = (r1 < L) ? r1 : 0;
      const float4* h0 = (const float4*)(hidden + ((size_t)(b * SEQL + c0 + 1)) * H);
      const float4* h1 = (const float4*)(hidden + ((size_t)(b * SEQL + c1 + 1)) * H);
#pragma unroll
      for (int k = 0; k < 3; ++k) { na[k] = h0[lane + 64 * k]; nb[k] = h1[lane + 64 * k]; }
    }
    float a0[T], a1[T];
#pragma unroll
    for (int t = 0; t < T; ++t) { a0[t] = 0.f; a1[t] = 0.f; }
#pragma unroll
    for (int t = 0; t < T; ++t) {
#pragma unroll
      for (int k = 0; k < 3; ++k) {
        float4 w = wl[t * 192 + lane + 64 * k];  // shared by both rows
        a0[t] = fmaf(ca[k].x, w.x, fmaf(ca[k].y, w.y, fmaf(ca[k].z, w.z, fmaf(ca[k].w, w.w, a0[t]))));
        a1[t] = fmaf(cb[k].x, w.x, fmaf(cb[k].y, w.y, fmaf(cb[k].z, w.z, fmaf(cb[k].w, w.w, a1[t]))));
      }
    }
#pragma unroll
    for (int off = 32; off; off >>= 1) {
#pragma unroll
      for (int t = 0; t < T; ++t) {
        a0[t] += __shfl_xor(a0[t], off);
        a1[t] += __shfl_xor(a1[t], off);
      }
    }
    if (lane < 2) {
      const bool vv = lane ? v1c : v0c;
      const int ii = lane ? i1c : i0c;
      if (vv) {
#pragma unroll
        for (int t = 0; t < T; ++t) {
          float v = (lane ? a1[t] : a0[t]) + bias[t];
          s_em[ii][t] = v;
          s_ee[ii][t] = __expf(v);
        }
      }
    }
    if (pr + 1 < npair) {                        // rotate pipeline
#pragma unroll
      for (int k = 0; k < 3; ++k) { ca[k] = na[k]; cb[k] = nb[k]; }
      i0c = i0n; i1c = i1n; v0c = v0n; v1c = v1n;
    }
  }
  __syncthreads();
  // ---- numerator terms for this block's rows (exact per-term rounding kept:
  //      term(l=0) = start+e; else trans+e; end term stored separately) ------
  if (threadIdx.x < 64) {
    const int r = threadIdx.x;
    const int l = row0 + r;
    if (l < L) {
      const int tg = labels[b * SEQL + 1 + l];
      const float e = s_em[r][tg];
      float term;
      if (l == 0) term = start_t[tg] + e;
      else term = s_tr[labels[b * SEQL + l] * 9 + tg] + e;
      sel[b * 512 + l] = term;
      if (l == L - 1) sel[b * 512 + 510] = end_t[tg];
    }
  }
  if (p == 0 && threadIdx.x < 12) em0[b * 12 + threadIdx.x] = s_em[0][threadIdx.x];
  // ---- chunk-scan phase: wv0/1 = den chunks, wv2/3 = viterbi chunks --------
  const int cb2 = wv & 1;
  const int sc_ = 2 * p + cb2;                   // global chunk id in [0,16)
  const int task = b * 16 + sc_;
  const int nt = (sc_ == 15) ? 29 : 32;
  const int base = 1 + 32 * cb2;                 // local row of chunk start
  const int i9 = (lane < 9) ? lane : 8;
  if (wv < 2) {
    // ---- den: running 9x9 transfer-matrix row in prob space + rescale ----
    // E[] is static-indexed only (stays in VGPRs); dynamic init reads s_tr.
    float E[81];
#pragma unroll
    for (int k = 0; k < 81; ++k) E[k] = __expf(s_tr[k]);
    float R[9];
#pragma unroll
    for (int j = 0; j < 9; ++j) R[j] = __expf(s_tr[i9 * 9 + j]) * s_ee[base][j];
    int iexp = 0;
    for (int t = 1; t < nt; ++t) {
      float Rn[9];
#pragma unroll
      for (int j = 0; j < 9; ++j) {
        float a = R[0] * E[j];
#pragma unroll
        for (int k = 1; k < 9; ++k) a = fmaf(R[k], E[k * 9 + j], a);
        Rn[j] = a;
      }
#pragma unroll
      for (int j = 0; j < 9; ++j) R[j] = Rn[j] * s_ee[base + t][j];
      if ((t & 3) == 0) {  // power-of-2 rescale
        float mx = R[0];
#pragma unroll
        for (int j = 1; j < 9; ++j) mx = fmaxf(mx, R[j]);
        int ex = (int)((__float_as_uint(mx) >> 23) & 0xff) - 127;
        iexp += ex;
        float sc = __uint_as_float((uint32_t)(127 - ex) << 23);
#pragma unroll
        for (int j = 0; j < 9; ++j) R[j] *= sc;
      }
    }
    if (lane < 9) {
      float ls = (float)iexp * LN2;
#pragma unroll
      for (int j = 0; j < 9; ++j)
        PdLn[(size_t)task * 81 + j * 9 + i9] = __logf(R[j]) + ls;
    }
  } else {
    // ---- viterbi max-plus transfer matrix, WITH backpointer recording ----
    // t_[] static-indexed only; dynamic init reads s_tr.
    float t_[81];
#pragma unroll
    for (int k = 0; k < 81; ++k) t_[k] = s_tr[k];
    float V[9];
#pragma unroll
    for (int j = 0; j < 9; ++j) V[j] = s_tr[i9 * 9 + j] + s_em[base][j];
    for (int t = 1; t < nt; ++t) {
      uint32_t lo = 0, hi = 0;
      float Vn[9];
#pragma unroll
      for (int j = 0; j < 9; ++j) {
        float best = V[0] + t_[0 * 9 + j];
        int bi = 0;
#pragma unroll
        for (int k = 1; k < 9; ++k) {
          float v = V[k] + t_[k * 9 + j];
          if (v > best) { best = v; bi = k; }
        }
        Vn[j] = best + s_em[base + t][j];
        if (j < 8) lo |= ((uint32_t)bi) << (4 * j);
        else hi = (uint32_t)bi;
      }
      if (lane < 9)
        Bp[(size_t)task * 288 + t * 9 + i9] =
            (unsigned long long)lo | ((unsigned long long)hi << 32);
#pragma unroll
      for (int j = 0; j < 9; ++j) V[j] = Vn[j];
    }
    if (lane < 9) {
#pragma unroll
      for (int j = 0; j < 9; ++j)
        Mv[(size_t)task * 81 + j * 9 + i9] = V[j];  // column-major [j][i]
    }
  }
}

// ---------------- K2: per-batch compose (256 thr, parallel waves) -----------
// wave0: numerator + den LSE compose + loss atomic.
// wave1: viterbi max-plus compose + final argmax + chunk-level chase.
// wave2: per-chunk backtrack straight from staged backpointers (no re-run).
__global__ __launch_bounds__(256) void compose_kernel(
    const float* __restrict__ sel, const float* __restrict__ em0,
    const float* __restrict__ PdLn, const float* __restrict__ Mv,
    const unsigned long long* __restrict__ Bp,
    const float* __restrict__ start_t, const float* __restrict__ end_t,
    float* __restrict__ out) {
  __shared__ __align__(16) float s_pd[16 * 81];
  __shared__ __align__(16) float s_mv[16 * 81];
  __shared__ __align__(16) unsigned long long s_bp[16 * 290];  // +2 u64 pad/chunk
  __shared__ float s_A[17 * 9];
  __shared__ int s_ch[16][2];
  const int b = blockIdx.x;
  const int tid = threadIdx.x;
  // ---- stage (all 256 threads, coalesced float4) ----
  {
    const float4* pdg = (const float4*)(PdLn + (size_t)b * 1296);
    const float4* mvg = (const float4*)(Mv + (size_t)b * 1296);
    for (int k = tid; k < 324; k += 256) {
      ((float4*)s_pd)[k] = pdg[k];
      ((float4*)s_mv)[k] = mvg[k];
    }
    const float4* bpg = (const float4*)(Bp + (size_t)b * 4608);
    for (int k = tid; k < 2304; k += 256) {
      const int s = k / 144, r = k - s * 144;
      ((float4*)&s_bp[s * 290])[r] = bpg[k];
    }
  }
  __syncthreads();
  const int wv = tid >> 6;
  const int lane = tid & 63;
  const int jj = lane < 9 ? lane : 8;

  if (wv == 0) {
    // ---- numerator: identical accumulation order ----
    float part_ = 0.f;
    for (int l = lane; l < L; l += 64) part_ += sel[b * 512 + l];
    if (lane == 61) part_ += sel[b * 512 + 510];  // end-term (l=509 -> lane 61)
#pragma unroll
    for (int off = 32; off; off >>= 1) part_ += __shfl_xor(part_, off);
    // ---- denominator: 16 LSE compose steps, lane j ----
    float D = start_t[jj] + em0[b * 12 + jj];
    for (int u = 0; u < 16; ++u) {
      const float* col = &s_pd[u * 81 + jj * 9];
      float v0 = rl(D, 0) + col[0], v1 = rl(D, 1) + col[1], v2 = rl(D, 2) + col[2];
      float v3 = rl(D, 3) + col[3], v4 = rl(D, 4) + col[4], v5 = rl(D, 5) + col[5];
      float v6 = rl(D, 6) + col[6], v7 = rl(D, 7) + col[7], v8 = rl(D, 8) + col[8];
      float mx = fmaxf(fmaxf(fmaxf(fmaxf(v0, v1), fmaxf(v2, v3)),
                             fmaxf(fmaxf(v4, v5), fmaxf(v6, v7))), v8);
      float sum = __expf(v0 - mx) + __expf(v1 - mx) + __expf(v2 - mx) +
                  __expf(v3 - mx) + __expf(v4 - mx) + __expf(v5 - mx) +
                  __expf(v6 - mx) + __expf(v7 - mx) + __expf(v8 - mx);
      D = mx + __logf(sum);
    }
    float fe = D + end_t[jj];
    float w0 = rl(fe, 0), w1 = rl(fe, 1), w2 = rl(fe, 2), w3 = rl(fe, 3);
    float w4 = rl(fe, 4), w5 = rl(fe, 5), w6 = rl(fe, 6), w7 = rl(fe, 7), w8 = rl(fe, 8);
    float mx = fmaxf(fmaxf(fmaxf(fmaxf(w0, w1), fmaxf(w2, w3)),
                           fmaxf(fmaxf(w4, w5), fmaxf(w6, w7))), w8);
    float den = mx + __logf(__expf(w0 - mx) + __expf(w1 - mx) + __expf(w2 - mx) +
                            __expf(w3 - mx) + __expf(w4 - mx) + __expf(w5 - mx) +
                            __expf(w6 - mx) + __expf(w7 - mx) + __expf(w8 - mx));
    if (lane == 0) atomicAdd(out, den - part_);  // out[0] = -sum(llh)
  } else if (wv == 1) {
    // ---- viterbi boundary alphas (max-plus compose), lane j ----
    float A = start_t[jj] + em0[b * 12 + jj];
    if (lane < 9) s_A[lane] = A;
    for (int u = 0; u < 16; ++u) {
      const float* col = &s_mv[u * 81 + jj * 9];
      float u0 = rl(A, 0) + col[0], u1 = rl(A, 1) + col[1], u2 = rl(A, 2) + col[2];
      float u3 = rl(A, 3) + col[3], u4 = rl(A, 4) + col[4], u5 = rl(A, 5) + col[5];
      float u6 = rl(A, 6) + col[6], u7 = rl(A, 7) + col[7], u8 = rl(A, 8) + col[8];
      A = fmaxf(fmaxf(fmaxf(fmaxf(u0, u1), fmaxf(u2, u3)),
                      fmaxf(fmaxf(u4, u5), fmaxf(u6, u7))), u8);
      if (lane < 9) s_A[(u + 1) * 9 + lane] = A;
    }
    // last tag: first-index argmax of A + end
    float fv = A + end_t[jj];
    int j = 0;
    {
      float bv = rl(fv, 0);
#pragma unroll
      for (int i = 1; i < 9; ++i) { float v = rl(fv, i); if (v > bv) { bv = v; j = i; } }
    }
    // ---- chunk-level backward chase ----
    for (int u = 15; u >= 0; --u) {
      float val = s_A[u * 9 + jj] + s_mv[u * 81 + j * 9 + jj];  // lane = entry state i
      int ii = 0;
      float bb = rl(val, 0);
#pragma unroll
      for (int i = 1; i < 9; ++i) { float v = rl(val, i); if (v > bb) { bb = v; ii = i; } }
      if (lane == 0) { s_ch[u][0] = ii; s_ch[u][1] = j; }
      j = ii;
    }
    if (lane == 0) out[1 + (size_t)b * L] = (float)j;  // tag at position 0
  }
  __syncthreads();
  // ---- per-chunk backtrack from backpointers (lane = chunk) ----
  if (wv == 2 && lane < 16) {
    const int s = lane;
    const int nt = (s == 15) ? 29 : 32;
    const int lb = 32 * s + 1;
    const int i0 = s_ch[s][0];
    int cur = s_ch[s][1];
    float* orow = out + 1 + (size_t)b * L + lb;
    for (int q = nt - 1; q >= 1; --q) {
      orow[q] = (float)cur;
      unsigned long long w = s_bp[s * 290 + q * 9 + i0];
      cur = (int)((w >> (4 * cur)) & 15ULL);
    }
    orow[0] = (float)cur;
  }
}

extern "C" void kernel_launch(void* const* d_in, const int* in_sizes, int n_in,
                              void* d_out, int out_size, void* d_ws, size_t ws_size,
                              hipStream_t stream) {
  const float* hidden  = (const float*)d_in[0];
  const int*   labels  = (const int*)d_in[1];
  const float* weight  = (const float*)d_in[2];
  const float* bias    = (const float*)d_in[3];
  const float* start_t = (const float*)d_in[4];
  const float* end_t   = (const float*)d_in[5];
  const float* trans   = (const float*)d_in[6];
  float* out = (float*)d_out;

  // workspace layout (16B-aligned blocks): ~3.16 MB total
  unsigned long long* Bp = (unsigned long long*)d_ws;   // 1024*288 u64 = 2359296 B
  float* sel  = (float*)(Bp + (size_t)1024 * 288);      // 64*512 f   =  131072 B
  float* em0  = sel + (size_t)64 * 512;                 // 64*12 f    =    3072 B
  float* PdLn = em0 + 768;                              // 1024*81 f  =  331776 B
  float* Mv   = PdLn + (size_t)1024 * 81;               // 1024*81 f  =  331776 B

  emis_chunk_kernel<<<512, 256, 0, stream>>>(hidden, weight, bias, trans,
                                             start_t, end_t, labels,
                                             sel, em0, PdLn, Mv, Bp, out);
  compose_kernel<<<NB, 256, 0, stream>>>(sel, em0, PdLn, Mv, Bp,
                                         start_t, end_t, out);
}

// Round 13
// 220.553 us; speedup vs baseline: 1.3785x; 1.0086x over previous
//
#include <hip/hip_runtime.h>
#include <stdint.h>

#define NB 64
#define SEQL 512
#define L 510
#define T 9
#define H 768
#define LN2 0.6931471805599453f

__device__ __forceinline__ float rl(float v, int l) {
  return __uint_as_float(__builtin_amdgcn_readlane(__float_as_uint(v), l));
}

// ---------------- K1: emissions + in-block chunk scans + numerator terms ----
// Grid: 64 batches x 8 row-groups. Block (b,p) computes em rows [64p, 64p+64]
// in LDS, then: (a) writes per-position numerator terms sel[b][l], (b) p==0
// writes em row 0 to em0, (c) 4 waves run the 4 chunk scans (den s=2p/2p+1,
// viterbi s=2p/2p+1 with backpointer recording) from LDS.
// r13 change vs the 222.46us-verified kernel: emission prefetch deepened from
// 1 pair to 2 pairs in flight (12 global loads/wave instead of 6). K1's wall
// tracks FETCH/achieved-BW (50MB @ 565GB/s ~ 88us ~ wall) -> raise MLP.
// Everything else verbatim. Buffers are named structs with static indexing
// (rule #20: no runtime-indexed register arrays).
// CRITICAL (rule #20): E[81]/t_[81] are indexed ONLY with compile-time
// constants (dynamic init reads go through LDS s_tr) else they spill (r2/r3:
// 44.5 MB scratch traffic, +80us). Watch WRITE_SIZE ~3.03MB: any jump = spill.
__global__ __launch_bounds__(256, 2) void emis_chunk_kernel(
    const float* __restrict__ hidden, const float* __restrict__ weight,
    const float* __restrict__ bias, const float* __restrict__ trans,
    const float* __restrict__ start_t, const float* __restrict__ end_t,
    const int* __restrict__ labels, float* __restrict__ sel,
    float* __restrict__ em0, float* __restrict__ PdLn, float* __restrict__ Mv,
    unsigned long long* __restrict__ Bp, float* __restrict__ out) {
  __shared__ float4 wl[T * 192];                 // 27648 B: 9 x 768 floats
  __shared__ __align__(16) float s_em[65][12];   // local rows 0..64
  __shared__ __align__(16) float s_ee[65][12];
  __shared__ float s_tr[81];                     // trans staged for dynamic reads
  const float4* w4 = (const float4*)weight;
  for (int k = threadIdx.x; k < T * 192; k += 256) wl[k] = w4[k];
  if (threadIdx.x < 81) s_tr[threadIdx.x] = trans[threadIdx.x];
  if (blockIdx.x == 0 && threadIdx.x == 0) out[0] = 0.f;  // atomic target init
  __syncthreads();
  const int b = blockIdx.x >> 3;
  const int p = blockIdx.x & 7;
  const int row0 = p * 64;                       // em-row base of this block
  const int lane = threadIdx.x & 63;
  const int wv = threadIdx.x >> 6;
  // ---- emission phase: wave wv owns local rows wv*16 .. wv*16+15 (pairs);
  //      wave 0 additionally computes local row 64 (first row of next group).
  //      2-deep software pipeline: pair pr+2's global loads issue before pair
  //      pr's compute -> 12 loads in flight per wave.
  const int npair = (wv == 0) ? 9 : 8;
  struct PairBuf {
    int i0, i1;
    bool v0, v1;
    float4 a[3], bv[3];
  };
  PairBuf cur, nxt, fut;
  auto issue = [&](int prn, PairBuf& P) {
    P.i0 = (prn < 8) ? (wv * 16 + prn * 2) : 64;
    P.i1 = (prn < 8) ? (P.i0 + 1) : 64;
    const int r0 = row0 + P.i0, r1 = row0 + P.i1;
    P.v0 = (r0 < L);
    P.v1 = (r1 < L) && (prn < 8);
    const int c0 = P.v0 ? r0 : 0;
    const int c1 = (r1 < L) ? r1 : 0;
    const float4* h0 = (const float4*)(hidden + ((size_t)(b * SEQL + c0 + 1)) * H);
    const float4* h1 = (const float4*)(hidden + ((size_t)(b * SEQL + c1 + 1)) * H);
#pragma unroll
    for (int k = 0; k < 3; ++k) { P.a[k] = h0[lane + 64 * k]; P.bv[k] = h1[lane + 64 * k]; }
  };
  issue(0, cur);
  if (npair > 1) issue(1, nxt);
#pragma unroll 1
  for (int pr = 0; pr < npair; ++pr) {
    if (pr + 2 < npair) issue(pr + 2, fut);      // 2-deep prefetch
    float a0[T], a1[T];
#pragma unroll
    for (int t = 0; t < T; ++t) { a0[t] = 0.f; a1[t] = 0.f; }
#pragma unroll
    for (int t = 0; t < T; ++t) {
#pragma unroll
      for (int k = 0; k < 3; ++k) {
        float4 w = wl[t * 192 + lane + 64 * k];  // shared by both rows
        a0[t] = fmaf(cur.a[k].x, w.x, fmaf(cur.a[k].y, w.y, fmaf(cur.a[k].z, w.z, fmaf(cur.a[k].w, w.w, a0[t]))));
        a1[t] = fmaf(cur.bv[k].x, w.x, fmaf(cur.bv[k].y, w.y, fmaf(cur.bv[k].z, w.z, fmaf(cur.bv[k].w, w.w, a1[t]))));
      }
    }
#pragma unroll
    for (int off = 32; off; off >>= 1) {
#pragma unroll
      for (int t = 0; t < T; ++t) {
        a0[t] += __shfl_xor(a0[t], off);
        a1[t] += __shfl_xor(a1[t], off);
      }
    }
    if (lane < 2) {
      const bool vv = lane ? cur.v1 : cur.v0;
      const int ii = lane ? cur.i1 : cur.i0;
      if (vv) {
#pragma unroll
        for (int t = 0; t < T; ++t) {
          float v = (lane ? a1[t] : a0[t]) + bias[t];
          s_em[ii][t] = v;
          s_ee[ii][t] = __expf(v);
        }
      }
    }
    if (pr + 1 < npair) {                        // rotate pipeline
      cur = nxt;
      nxt = fut;
    }
  }
  __syncthreads();
  // ---- numerator terms for this block's rows (exact per-term rounding kept:
  //      term(l=0) = start+e; else trans+e; end term stored separately) ------
  if (threadIdx.x < 64) {
    const int r = threadIdx.x;
    const int l = row0 + r;
    if (l < L) {
      const int tg = labels[b * SEQL + 1 + l];
      const float e = s_em[r][tg];
      float term;
      if (l == 0) term = start_t[tg] + e;
      else term = s_tr[labels[b * SEQL + l] * 9 + tg] + e;
      sel[b * 512 + l] = term;
      if (l == L - 1) sel[b * 512 + 510] = end_t[tg];
    }
  }
  if (p == 0 && threadIdx.x < 12) em0[b * 12 + threadIdx.x] = s_em[0][threadIdx.x];
  // ---- chunk-scan phase: wv0/1 = den chunks, wv2/3 = viterbi chunks --------
  const int cb2 = wv & 1;
  const int sc_ = 2 * p + cb2;                   // global chunk id in [0,16)
  const int task = b * 16 + sc_;
  const int nt = (sc_ == 15) ? 29 : 32;
  const int base = 1 + 32 * cb2;                 // local row of chunk start
  const int i9 = (lane < 9) ? lane : 8;
  if (wv < 2) {
    // ---- den: running 9x9 transfer-matrix row in prob space + rescale ----
    // E[] is static-indexed only (stays in VGPRs); dynamic init reads s_tr.
    float E[81];
#pragma unroll
    for (int k = 0; k < 81; ++k) E[k] = __expf(s_tr[k]);
    float R[9];
#pragma unroll
    for (int j = 0; j < 9; ++j) R[j] = __expf(s_tr[i9 * 9 + j]) * s_ee[base][j];
    int iexp = 0;
    for (int t = 1; t < nt; ++t) {
      float Rn[9];
#pragma unroll
      for (int j = 0; j < 9; ++j) {
        float a = R[0] * E[j];
#pragma unroll
        for (int k = 1; k < 9; ++k) a = fmaf(R[k], E[k * 9 + j], a);
        Rn[j] = a;
      }
#pragma unroll
      for (int j = 0; j < 9; ++j) R[j] = Rn[j] * s_ee[base + t][j];
      if ((t & 3) == 0) {  // power-of-2 rescale
        float mx = R[0];
#pragma unroll
        for (int j = 1; j < 9; ++j) mx = fmaxf(mx, R[j]);
        int ex = (int)((__float_as_uint(mx) >> 23) & 0xff) - 127;
        iexp += ex;
        float sc = __uint_as_float((uint32_t)(127 - ex) << 23);
#pragma unroll
        for (int j = 0; j < 9; ++j) R[j] *= sc;
      }
    }
    if (lane < 9) {
      float ls = (float)iexp * LN2;
#pragma unroll
      for (int j = 0; j < 9; ++j)
        PdLn[(size_t)task * 81 + j * 9 + i9] = __logf(R[j]) + ls;
    }
  } else {
    // ---- viterbi max-plus transfer matrix, WITH backpointer recording ----
    // t_[] static-indexed only; dynamic init reads s_tr.
    float t_[81];
#pragma unroll
    for (int k = 0; k < 81; ++k) t_[k] = s_tr[k];
    float V[9];
#pragma unroll
    for (int j = 0; j < 9; ++j) V[j] = s_tr[i9 * 9 + j] + s_em[base][j];
    for (int t = 1; t < nt; ++t) {
      uint32_t lo = 0, hi = 0;
      float Vn[9];
#pragma unroll
      for (int j = 0; j < 9; ++j) {
        float best = V[0] + t_[0 * 9 + j];
        int bi = 0;
#pragma unroll
        for (int k = 1; k < 9; ++k) {
          float v = V[k] + t_[k * 9 + j];
          if (v > best) { best = v; bi = k; }
        }
        Vn[j] = best + s_em[base + t][j];
        if (j < 8) lo |= ((uint32_t)bi) << (4 * j);
        else hi = (uint32_t)bi;
      }
      if (lane < 9)
        Bp[(size_t)task * 288 + t * 9 + i9] =
            (unsigned long long)lo | ((unsigned long long)hi << 32);
#pragma unroll
      for (int j = 0; j < 9; ++j) V[j] = Vn[j];
    }
    if (lane < 9) {
#pragma unroll
      for (int j = 0; j < 9; ++j)
        Mv[(size_t)task * 81 + j * 9 + i9] = V[j];  // column-major [j][i]
    }
  }
}

// ---------------- K2: per-batch compose (256 thr, parallel waves) -----------
// wave0: numerator + den LSE compose + loss atomic.
// wave1: viterbi max-plus compose + final argmax + chunk-level chase.
// wave2: per-chunk backtrack straight from staged backpointers (no re-run).
__global__ __launch_bounds__(256) void compose_kernel(
    const float* __restrict__ sel, const float* __restrict__ em0,
    const float* __restrict__ PdLn, const float* __restrict__ Mv,
    const unsigned long long* __restrict__ Bp,
    const float* __restrict__ start_t, const float* __restrict__ end_t,
    float* __restrict__ out) {
  __shared__ __align__(16) float s_pd[16 * 81];
  __shared__ __align__(16) float s_mv[16 * 81];
  __shared__ __align__(16) unsigned long long s_bp[16 * 290];  // +2 u64 pad/chunk
  __shared__ float s_A[17 * 9];
  __shared__ int s_ch[16][2];
  const int b = blockIdx.x;
  const int tid = threadIdx.x;
  // ---- stage (all 256 threads, coalesced float4) ----
  {
    const float4* pdg = (const float4*)(PdLn + (size_t)b * 1296);
    const float4* mvg = (const float4*)(Mv + (size_t)b * 1296);
    for (int k = tid; k < 324; k += 256) {
      ((float4*)s_pd)[k] = pdg[k];
      ((float4*)s_mv)[k] = mvg[k];
    }
    const float4* bpg = (const float4*)(Bp + (size_t)b * 4608);
    for (int k = tid; k < 2304; k += 256) {
      const int s = k / 144, r = k - s * 144;
      ((float4*)&s_bp[s * 290])[r] = bpg[k];
    }
  }
  __syncthreads();
  const int wv = tid >> 6;
  const int lane = tid & 63;
  const int jj = lane < 9 ? lane : 8;

  if (wv == 0) {
    // ---- numerator: identical accumulation order ----
    float part_ = 0.f;
    for (int l = lane; l < L; l += 64) part_ += sel[b * 512 + l];
    if (lane == 61) part_ += sel[b * 512 + 510];  // end-term (l=509 -> lane 61)
#pragma unroll
    for (int off = 32; off; off >>= 1) part_ += __shfl_xor(part_, off);
    // ---- denominator: 16 LSE compose steps, lane j ----
    float D = start_t[jj] + em0[b * 12 + jj];
    for (int u = 0; u < 16; ++u) {
      const float* col = &s_pd[u * 81 + jj * 9];
      float v0 = rl(D, 0) + col[0], v1 = rl(D, 1) + col[1], v2 = rl(D, 2) + col[2];
      float v3 = rl(D, 3) + col[3], v4 = rl(D, 4) + col[4], v5 = rl(D, 5) + col[5];
      float v6 = rl(D, 6) + col[6], v7 = rl(D, 7) + col[7], v8 = rl(D, 8) + col[8];
      float mx = fmaxf(fmaxf(fmaxf(fmaxf(v0, v1), fmaxf(v2, v3)),
                             fmaxf(fmaxf(v4, v5), fmaxf(v6, v7))), v8);
      float sum = __expf(v0 - mx) + __expf(v1 - mx) + __expf(v2 - mx) +
                  __expf(v3 - mx) + __expf(v4 - mx) + __expf(v5 - mx) +
                  __expf(v6 - mx) + __expf(v7 - mx) + __expf(v8 - mx);
      D = mx + __logf(sum);
    }
    float fe = D + end_t[jj];
    float w0 = rl(fe, 0), w1 = rl(fe, 1), w2 = rl(fe, 2), w3 = rl(fe, 3);
    float w4 = rl(fe, 4), w5 = rl(fe, 5), w6 = rl(fe, 6), w7 = rl(fe, 7), w8 = rl(fe, 8);
    float mx = fmaxf(fmaxf(fmaxf(fmaxf(w0, w1), fmaxf(w2, w3)),
                           fmaxf(fmaxf(w4, w5), fmaxf(w6, w7))), w8);
    float den = mx + __logf(__expf(w0 - mx) + __expf(w1 - mx) + __expf(w2 - mx) +
                            __expf(w3 - mx) + __expf(w4 - mx) + __expf(w5 - mx) +
                            __expf(w6 - mx) + __expf(w7 - mx) + __expf(w8 - mx));
    if (lane == 0) atomicAdd(out, den - part_);  // out[0] = -sum(llh)
  } else if (wv == 1) {
    // ---- viterbi boundary alphas (max-plus compose), lane j ----
    float A = start_t[jj] + em0[b * 12 + jj];
    if (lane < 9) s_A[lane] = A;
    for (int u = 0; u < 16; ++u) {
      const float* col = &s_mv[u * 81 + jj * 9];
      float u0 = rl(A, 0) + col[0], u1 = rl(A, 1) + col[1], u2 = rl(A, 2) + col[2];
      float u3 = rl(A, 3) + col[3], u4 = rl(A, 4) + col[4], u5 = rl(A, 5) + col[5];
      float u6 = rl(A, 6) + col[6], u7 = rl(A, 7) + col[7], u8 = rl(A, 8) + col[8];
      A = fmaxf(fmaxf(fmaxf(fmaxf(u0, u1), fmaxf(u2, u3)),
                      fmaxf(fmaxf(u4, u5), fmaxf(u6, u7))), u8);
      if (lane < 9) s_A[(u + 1) * 9 + lane] = A;
    }
    // last tag: first-index argmax of A + end
    float fv = A + end_t[jj];
    int j = 0;
    {
      float bv = rl(fv, 0);
#pragma unroll
      for (int i = 1; i < 9; ++i) { float v = rl(fv, i); if (v > bv) { bv = v; j = i; } }
    }
    // ---- chunk-level backward chase ----
    for (int u = 15; u >= 0; --u) {
      float val = s_A[u * 9 + jj] + s_mv[u * 81 + j * 9 + jj];  // lane = entry state i
      int ii = 0;
      float bb = rl(val, 0);
#pragma unroll
      for (int i = 1; i < 9; ++i) { float v = rl(val, i); if (v > bb) { bb = v; ii = i; } }
      if (lane == 0) { s_ch[u][0] = ii; s_ch[u][1] = j; }
      j = ii;
    }
    if (lane == 0) out[1 + (size_t)b * L] = (float)j;  // tag at position 0
  }
  __syncthreads();
  // ---- per-chunk backtrack from backpointers (lane = chunk) ----
  if (wv == 2 && lane < 16) {
    const int s = lane;
    const int nt = (s == 15) ? 29 : 32;
    const int lb = 32 * s + 1;
    const int i0 = s_ch[s][0];
    int cur = s_ch[s][1];
    float* orow = out + 1 + (size_t)b * L + lb;
    for (int q = nt - 1; q >= 1; --q) {
      orow[q] = (float)cur;
      unsigned long long w = s_bp[s * 290 + q * 9 + i0];
      cur = (int)((w >> (4 * cur)) & 15ULL);
    }
    orow[0] = (float)cur;
  }
}

extern "C" void kernel_launch(void* const* d_in, const int* in_sizes, int n_in,
                              void* d_out, int out_size, void* d_ws, size_t ws_size,
                              hipStream_t stream) {
  const float* hidden  = (const float*)d_in[0];
  const int*   labels  = (const int*)d_in[1];
  const float* weight  = (const float*)d_in[2];
  const float* bias    = (const float*)d_in[3];
  const float* start_t = (const float*)d_in[4];
  const float* end_t   = (const float*)d_in[5];
  const float* trans   = (const float*)d_in[6];
  float* out = (float*)d_out;

  // workspace layout (16B-aligned blocks): ~3.16 MB total
  unsigned long long* Bp = (unsigned long long*)d_ws;   // 1024*288 u64 = 2359296 B
  float* sel  = (float*)(Bp + (size_t)1024 * 288);      // 64*512 f   =  131072 B
  float* em0  = sel + (size_t)64 * 512;                 // 64*12 f    =    3072 B
  float* PdLn = em0 + 768;                              // 1024*81 f  =  331776 B
  float* Mv   = PdLn + (size_t)1024 * 81;               // 1024*81 f  =  331776 B

  emis_chunk_kernel<<<512, 256, 0, stream>>>(hidden, weight, bias, trans,
                                             start_t, end_t, labels,
                                             sel, em0, PdLn, Mv, Bp, out);
  compose_kernel<<<NB, 256, 0, stream>>>(sel, em0, PdLn, Mv, Bp,
                                         start_t, end_t, out);
}